// Round 8
// baseline (380.446 us; speedup 1.0000x reference)
//
#include <hip/hip_runtime.h>
#include <math.h>

#define Bb 512
#define Tt 512
#define Kk 128
#define NSTART 126   // K-2
#define NSTOP  127   // K-1

static constexpr float LOG2E = 1.4426950408889634f;
static constexpr float LN2   = 0.6931471805599453f;

__device__ __forceinline__ float fexp2(float x){ return __builtin_amdgcn_exp2f(x); }
__device__ __forceinline__ float flog2(float x){ return __builtin_amdgcn_logf(x); }
__device__ __forceinline__ float frcp (float x){ return __builtin_amdgcn_rcpf(x); }

// d = a.lo*b.lo + a.hi*b.hi + c  (packed fp16 inputs, fp32 accumulate)
__device__ __forceinline__ float dot2f16(unsigned int a, unsigned int b, float c){
  float d; asm("v_dot2_f32_f16 %0, %1, %2, %3" : "=v"(d) : "v"(a), "v"(b), "v"(c)); return d;
}
// pack two f32 -> packed f16 {lo, hi} (round toward zero)
__device__ __forceinline__ unsigned int pk2f16(float lo, float hi){
  unsigned int u; asm("v_cvt_pkrtz_f16_f32 %0, %1, %2" : "=v"(u) : "v"(lo), "v"(hi)); return u;
}
// f16 (low 16 bits of u) -> f32
__device__ __forceinline__ float cvt_f32_f16(unsigned int u){
  float f; asm("v_cvt_f32_f16 %0, %1" : "=v"(f) : "v"(u)); return f;
}

template<int CTRL>
__device__ __forceinline__ float dpp_mov(float s){
  union {float f; int i;} a, r; a.f = s;
  r.i = __builtin_amdgcn_update_dpp(a.i, a.i, CTRL, 0xf, 0xf, false);
  return r.f;
}
#define QP_BCAST0 0x00   // quad_perm [0,0,0,0]
#define QP_XOR1   0xB1   // quad_perm [1,0,3,2]
#define QP_XOR2   0x4E   // quad_perm [2,3,0,1]

// ---- one CRF chain per 64-lane wave; zero barriers ----
// lane l: q = l&3 (prev-quarter: 32 states), nb = l>>2 (8 contiguous next rows
// r0=8nb..8nb+7). Linear-space recursion a_new[n] = exp(feat[n]) * sum_p E[n,p]a[p].
// E = exp(trans) packed fp16 in 128 VGPRs. Alpha: 128 fp16 in 256B LDS, single
// buffer (wave-lockstep + in-order DS pipe => no sync needed). Renormalize wave
// max -> 1 EVERY step (fp16 range: per-step growth <= ~2e4, held fp32 until
// post-renorm store). q-partials combined with DPP quad_perm adds (VALU-only).
__global__ __launch_bounds__(64, 1) void crf_wave(
    const float* __restrict__ feats,   // [B,T,K]
    const int*   __restrict__ tags,    // [B,T]
    const float* __restrict__ trans,   // [K,K]  trans[next, prev]
    float* __restrict__ part)          // [B]
{
  const int b  = blockIdx.x;
  const int l  = threadIdx.x;   // 0..63
  const int q  = l & 3;
  const int nb = l >> 2;        // 0..15
  const int r0 = nb * 8;        // first of this lane's 8 next-rows
  const int q4 = q * 4;         // uint4 index of this lane's prev-quarter

  __shared__ unsigned int aP[Kk/2];   // fp16 pairs: dword d = rows 2d(lo), 2d+1(hi)

  // ---- E in regs: E[r][jj] = {exp(tr[r0+r, q*32+2jj]), exp(tr[r0+r, q*32+2jj+1])} ----
  unsigned int E[8][16];
  #pragma unroll
  for (int r = 0; r < 8; ++r) {
    const float* tr = trans + (size_t)(r0 + r) * Kk + q * 32;
    #pragma unroll
    for (int j4 = 0; j4 < 8; ++j4) {
      float4 v = *(const float4*)(tr + 4 * j4);
      E[r][2*j4+0] = pk2f16(fexp2(v.x * LOG2E), fexp2(v.y * LOG2E));
      E[r][2*j4+1] = pk2f16(fexp2(v.z * LOG2E), fexp2(v.w * LOG2E));
    }
  }
  #pragma unroll
  for (int r = 0; r < 8; ++r)
    #pragma unroll
    for (int j = 0; j < 16; ++j)
      asm volatile("" : "+v"(E[r][j]));   // keep resident

  // ---- alpha0: fp16 1.0 at row START(126) = dword 63 low half ----
  aP[l] = (l == 63) ? 0x00003C00u : 0u;   // wave-internal, in-order DS: no barrier

  const float* fbr = feats + (size_t)b * Tt * Kk + r0;  // this lane's row base
  float C2 = 0.0f;                                      // renorm offset, log2 units

  // feats pipeline (q==0 lanes only), 2 steps deep, ping-pong (no reg moves)
  float4 A0 = {0,0,0,0}, A1 = {0,0,0,0}, B0 = {0,0,0,0}, B1 = {0,0,0,0};
  if (q == 0) {
    A0 = *(const float4*)(fbr);            A1 = *(const float4*)(fbr + 4);
    B0 = *(const float4*)(fbr + Kk);       B1 = *(const float4*)(fbr + Kk + 4);
  }

#define DOT4(AV, J0)                                                            \
  { const unsigned int d0=AV.x, d1=AV.y, d2=AV.z, d3=AV.w;                      \
    _Pragma("unroll") for (int r = 0; r < 8; ++r) {                             \
      aA[r] = dot2f16(E[r][J0+0], d0, aA[r]);                                   \
      aB[r] = dot2f16(E[r][J0+1], d1, aB[r]);                                   \
      aA[r] = dot2f16(E[r][J0+2], d2, aA[r]);                                   \
      aB[r] = dot2f16(E[r][J0+3], d3, aB[r]); } }

#define STEP(CA0, CA1, TT)                                                      \
  {                                                                             \
    const uint4* ap4 = (const uint4*)aP;                                        \
    uint4 av0 = ap4[q4+0], av1 = ap4[q4+1], av2 = ap4[q4+2], av3 = ap4[q4+3];   \
    float fr[8] = {CA0.x, CA0.y, CA0.z, CA0.w, CA1.x, CA1.y, CA1.z, CA1.w};     \
    if (q == 0) {                                                               \
      int tl = (TT) + 2; if (tl > Tt - 1) tl = Tt - 1;                          \
      CA0 = *(const float4*)(fbr + (size_t)tl * Kk);                            \
      CA1 = *(const float4*)(fbr + (size_t)tl * Kk + 4);                        \
    }                                                                           \
    float ex[8];                                                                \
    _Pragma("unroll") for (int r = 0; r < 8; ++r)                               \
      ex[r] = fexp2(dpp_mov<QP_BCAST0>(fr[r]) * LOG2E);                         \
    float aA[8], aB[8];                                                         \
    _Pragma("unroll") for (int r = 0; r < 8; ++r) { aA[r] = 0.f; aB[r] = 0.f; } \
    DOT4(av0, 0) DOT4(av1, 4) DOT4(av2, 8) DOT4(av3, 12)                        \
    float y[8];                                                                 \
    _Pragma("unroll") for (int r = 0; r < 8; ++r) {                             \
      float s = aA[r] + aB[r];                                                  \
      s = s + dpp_mov<QP_XOR1>(s);                                              \
      s = s + dpp_mov<QP_XOR2>(s);                                              \
      y[r] = ex[r] * s;                                                         \
    }                                                                           \
    float m = fmaxf(fmaxf(fmaxf(y[0],y[1]), fmaxf(y[2],y[3])),                  \
                    fmaxf(fmaxf(y[4],y[5]), fmaxf(y[6],y[7])));                 \
    m = fmaxf(m, __shfl_xor(m,  4, 64));                                        \
    m = fmaxf(m, __shfl_xor(m,  8, 64));                                        \
    m = fmaxf(m, __shfl_xor(m, 16, 64));                                        \
    m = fmaxf(m, __shfl_xor(m, 32, 64));                                        \
    C2 += flog2(m);                                                             \
    const float inv = frcp(m);                                                  \
    unsigned int p0 = pk2f16(y[0]*inv, y[1]*inv);                               \
    unsigned int p1 = pk2f16(y[2]*inv, y[3]*inv);                               \
    unsigned int p2 = pk2f16(y[4]*inv, y[5]*inv);                               \
    unsigned int p3 = pk2f16(y[6]*inv, y[7]*inv);                               \
    if (q == 0) {                                                               \
      uint4 pv; pv.x = p0; pv.y = p1; pv.z = p2; pv.w = p3;                     \
      ((uint4*)aP)[nb] = pv;                                                    \
    }                                                                           \
  }

  for (int t = 0; t < Tt; t += 2) {
    STEP(A0, A1, t)
    STEP(B0, B1, t + 1)
  }

  // ---- forward score: ln( sum_n a[n] * exp(T[STOP,n]) ) + offset ----
  {
    const unsigned int d = aP[l];          // rows 2l (lo), 2l+1 (hi)
    const float a0 = cvt_f32_f16(d);
    const float a1 = cvt_f32_f16(d >> 16);
    const float e0 = fexp2(trans[(size_t)NSTOP * Kk + 2*l]     * LOG2E);
    const float e1 = fexp2(trans[(size_t)NSTOP * Kk + 2*l + 1] * LOG2E);
    float v = a0 * e0 + a1 * e1;
    #pragma unroll
    for (int off = 32; off >= 1; off >>= 1) v += __shfl_xor(v, off, 64);
    const float fwd = LN2 * (C2 + flog2(v));

    // ---- gold path score (8 timesteps per lane) ----
    const int* tg = tags + (size_t)b * Tt;
    const float* fbase = feats + (size_t)b * Tt * Kk;
    float g = 0.0f;
    #pragma unroll
    for (int k2 = 0; k2 < Tt / 64; ++k2) {
      const int tt   = l + 64 * k2;
      const int curt = tg[tt];
      const int prv  = (tt == 0) ? NSTART : tg[tt - 1];
      g += trans[(size_t)curt * Kk + prv] + fbase[(size_t)tt * Kk + curt];
    }
    if (l == 0) g += trans[(size_t)NSTOP * Kk + tg[Tt - 1]];
    #pragma unroll
    for (int off = 32; off >= 1; off >>= 1) g += __shfl_xor(g, off, 64);

    if (l == 0) part[b] = fwd - g;
  }
}

__global__ __launch_bounds__(256) void reduce_mean_kernel(
    const float* __restrict__ part, float* __restrict__ out)
{
  __shared__ float buf[4];
  const int tid = threadIdx.x;
  float v = part[tid] + part[tid + 256];
  #pragma unroll
  for (int off = 32; off >= 1; off >>= 1) v += __shfl_xor(v, off, 64);
  if ((tid & 63) == 0) buf[tid >> 6] = v;
  __syncthreads();
  if (tid == 0)
    out[0] = (buf[0] + buf[1] + buf[2] + buf[3]) * (1.0f / (float)Bb);
}

extern "C" void kernel_launch(void* const* d_in, const int* in_sizes, int n_in,
                              void* d_out, int out_size, void* d_ws, size_t ws_size,
                              hipStream_t stream) {
  const float* feats = (const float*)d_in[0];
  const int*   tags  = (const int*)d_in[1];
  const float* trans = (const float*)d_in[2];
  float* part = (float*)d_ws;

  crf_wave<<<dim3(Bb), dim3(64), 0, stream>>>(feats, tags, trans, part);
  reduce_mean_kernel<<<dim3(1), dim3(256), 0, stream>>>(part, (float*)d_out);
}

// Round 9
// 270.385 us; speedup vs baseline: 1.4071x; 1.4071x over previous
//
#include <hip/hip_runtime.h>
#include <math.h>

#define Bb 512
#define Tt 512
#define Kk 128
#define NSTART 126   // K-2
#define NSTOP  127   // K-1

static constexpr float LOG2E = 1.4426950408889634f;
static constexpr float LN2   = 0.6931471805599453f;

__device__ __forceinline__ float fexp2(float x){ return __builtin_amdgcn_exp2f(x); }
__device__ __forceinline__ float flog2(float x){ return __builtin_amdgcn_logf(x); }
__device__ __forceinline__ float frcp (float x){ return __builtin_amdgcn_rcpf(x); }

// acc += e.lo*s.lo + e.hi*s.hi   (packed fp16, fp32 accum; s is an SGPR broadcast)
__device__ __forceinline__ void dot2a(float& acc, unsigned int e, int s){
  asm("v_dot2_f32_f16 %0, %1, %2, %0" : "+v"(acc) : "v"(e), "s"(s));
}
// pack two f32 -> packed f16 {lo, hi}
__device__ __forceinline__ unsigned int pk2f16(float lo, float hi){
  unsigned int u; asm("v_cvt_pkrtz_f16_f32 %0, %1, %2" : "=v"(u) : "v"(lo), "v"(hi)); return u;
}
__device__ __forceinline__ float cvt_f32_f16(unsigned int u){
  float f; asm("v_cvt_f32_f16 %0, %1" : "=v"(f) : "v"(u)); return f;
}

template<int CTRL>
__device__ __forceinline__ float dpp_mov(float s){
  union {float f; int i;} a, r; a.f = s;
  r.i = __builtin_amdgcn_update_dpp(a.i, a.i, CTRL, 0xf, 0xf, false);
  return r.f;
}
#define QP_XOR1  0xB1    // quad_perm [1,0,3,2]
#define QP_XOR2  0x4E    // quad_perm [2,3,0,1]
#define ROW_ROR4 0x124   // row_ror:4
#define ROW_ROR8 0x128   // row_ror:8

__device__ __forceinline__ float rlanef(float x, int lane){
  union {float f; int i;} v; v.f = x;
  union {int i; float f;} r; r.i = __builtin_amdgcn_readlane(v.i, lane);
  return r.f;
}

// ---- one CRF chain per 64-lane wave; NO LDS, NO barriers, NO DS ops in loop ----
// Lane l owns next-states {2l, 2l+1}. Alpha (128 fp16) lives in registers: one
// dword per lane (states 2l lo, 2l+1 hi). Per step, each lane's alpha dword is
// broadcast to the wave via v_readlane (SGPR) and consumed by v_dot2_f32_f16
// against E rows held as packed fp16 in 128 VGPRs. Renorm (wave max -> 1) every
// step, computed with DPP quad_perm/row_ror + 4 readlanes (pure VALU, no
// ds_swizzle). Feats prefetched 4 steps ahead. fp16 range: post-renorm alpha
// in [0,1]; one-step growth <= 128*e^5.5*e^5.5 ~ 8e6 held in fp32, renormed
// before fp16 pack.
__global__ __launch_bounds__(64, 1) void crf_rl(
    const float* __restrict__ feats,   // [B,T,K]
    const int*   __restrict__ tags,    // [B,T]
    const float* __restrict__ trans,   // [K,K]  trans[next, prev]
    float* __restrict__ part)          // [B]
{
  const int b = blockIdx.x;
  const int l = threadIdx.x;   // 0..63

  // ---- E rows 2l, 2l+1 as packed fp16 pairs along prev: 128 VGPRs ----
  unsigned int E0[64], E1[64];
  {
    const float* t0 = trans + (size_t)(2*l)     * Kk;
    const float* t1 = trans + (size_t)(2*l + 1) * Kk;
    #pragma unroll
    for (int j = 0; j < 64; ++j) {
      float2 v0 = *(const float2*)(t0 + 2*j);
      float2 v1 = *(const float2*)(t1 + 2*j);
      E0[j] = pk2f16(fexp2(v0.x * LOG2E), fexp2(v0.y * LOG2E));
      E1[j] = pk2f16(fexp2(v1.x * LOG2E), fexp2(v1.y * LOG2E));
    }
  }
  #pragma unroll
  for (int j = 0; j < 64; ++j)
    asm volatile("" : "+v"(E0[j]), "+v"(E1[j]));

  // alpha0: state 126 = 1.0 (lane 63 lo half), else 0
  unsigned int a = (l == 63) ? 0x00003C00u : 0u;

  const float* fp2 = feats + (size_t)b * Tt * Kk + 2*l;  // this lane's 2 states
  float2 F[4];
  #pragma unroll
  for (int i = 0; i < 4; ++i) F[i] = *(const float2*)(fp2 + (size_t)i * Kk);

  float C2 = 0.0f;   // renorm offset, log2 units (wave-uniform)

  for (int t = 0; t < Tt; t += 4) {
    #pragma unroll
    for (int u = 0; u < 4; ++u) {
      const float f0 = F[u].x, f1 = F[u].y;
      {  // refill ring slot for step t+4+u (clamped; harmless re-read at tail)
        int tn = t + 4 + u; if (tn > Tt - 1) tn = Tt - 1;
        F[u] = *(const float2*)(fp2 + (size_t)tn * Kk);
      }

      float A0=0.f,A1=0.f,A2=0.f,A3=0.f, B0=0.f,B1=0.f,B2=0.f,B3=0.f;
      #pragma unroll
      for (int i = 0; i < 64; i += 4) {
        const int s0 = __builtin_amdgcn_readlane((int)a, i+0);
        const int s1 = __builtin_amdgcn_readlane((int)a, i+1);
        const int s2 = __builtin_amdgcn_readlane((int)a, i+2);
        const int s3 = __builtin_amdgcn_readlane((int)a, i+3);
        dot2a(A0, E0[i+0], s0);  dot2a(B0, E1[i+0], s0);
        dot2a(A1, E0[i+1], s1);  dot2a(B1, E1[i+1], s1);
        dot2a(A2, E0[i+2], s2);  dot2a(B2, E1[i+2], s2);
        dot2a(A3, E0[i+3], s3);  dot2a(B3, E1[i+3], s3);
      }
      const float sA = (A0 + A1) + (A2 + A3);
      const float sB = (B0 + B1) + (B2 + B3);
      float y0 = fexp2(f0 * LOG2E) * sA;
      float y1 = fexp2(f1 * LOG2E) * sB;

      // ---- wave max -> renorm, pure VALU (DPP) + readlane ----
      float m = fmaxf(y0, y1);
      m = fmaxf(m, dpp_mov<QP_XOR1>(m));
      m = fmaxf(m, dpp_mov<QP_XOR2>(m));
      m = fmaxf(m, dpp_mov<ROW_ROR4>(m));
      m = fmaxf(m, dpp_mov<ROW_ROR8>(m));   // all lanes: 16-lane row max
      const float mm = fmaxf(fmaxf(rlanef(m, 0),  rlanef(m, 16)),
                             fmaxf(rlanef(m, 32), rlanef(m, 48)));
      C2 += flog2(mm);
      const float inv = frcp(mm);
      a = pk2f16(y0 * inv, y1 * inv);
    }
  }

  // ---- forward score: ln( sum_n a[n] * exp(T[STOP,n]) ) + offset ----
  {
    const float a0 = cvt_f32_f16(a);
    const float a1 = cvt_f32_f16(a >> 16);
    const float e0 = fexp2(trans[(size_t)NSTOP * Kk + 2*l]     * LOG2E);
    const float e1 = fexp2(trans[(size_t)NSTOP * Kk + 2*l + 1] * LOG2E);
    float v = a0 * e0 + a1 * e1;
    #pragma unroll
    for (int off = 32; off >= 1; off >>= 1) v += __shfl_xor(v, off, 64);
    const float fwd = LN2 * (C2 + flog2(v));

    // ---- gold path score (8 timesteps per lane; exact fp32) ----
    const int* tg = tags + (size_t)b * Tt;
    const float* fbase = feats + (size_t)b * Tt * Kk;
    float g = 0.0f;
    #pragma unroll
    for (int k2 = 0; k2 < Tt / 64; ++k2) {
      const int tt   = l + 64 * k2;
      const int curt = tg[tt];
      const int prv  = (tt == 0) ? NSTART : tg[tt - 1];
      g += trans[(size_t)curt * Kk + prv] + fbase[(size_t)tt * Kk + curt];
    }
    if (l == 0) g += trans[(size_t)NSTOP * Kk + tg[Tt - 1]];
    #pragma unroll
    for (int off = 32; off >= 1; off >>= 1) g += __shfl_xor(g, off, 64);

    if (l == 0) part[b] = fwd - g;
  }
}

__global__ __launch_bounds__(256) void reduce_mean_kernel(
    const float* __restrict__ part, float* __restrict__ out)
{
  __shared__ float buf[4];
  const int tid = threadIdx.x;
  float v = part[tid] + part[tid + 256];
  #pragma unroll
  for (int off = 32; off >= 1; off >>= 1) v += __shfl_xor(v, off, 64);
  if ((tid & 63) == 0) buf[tid >> 6] = v;
  __syncthreads();
  if (tid == 0)
    out[0] = (buf[0] + buf[1] + buf[2] + buf[3]) * (1.0f / (float)Bb);
}

extern "C" void kernel_launch(void* const* d_in, const int* in_sizes, int n_in,
                              void* d_out, int out_size, void* d_ws, size_t ws_size,
                              hipStream_t stream) {
  const float* feats = (const float*)d_in[0];
  const int*   tags  = (const int*)d_in[1];
  const float* trans = (const float*)d_in[2];
  float* part = (float*)d_ws;

  crf_rl<<<dim3(Bb), dim3(64), 0, stream>>>(feats, tags, trans, part);
  reduce_mean_kernel<<<dim3(1), dim3(256), 0, stream>>>(part, (float*)d_out);
}